// Round 8
// baseline (557.581 us; speedup 1.0000x reference)
//
#include <hip/hip_runtime.h>
#include <cstdint>
#include <cstddef>

// Problem dims (fixed)
#define CDIM 8192
#define NDIM 1024   // H*W
#define C8D  1024
#define MSTACK 10240  // 8192 (v) + 1024 (q) + 1024 (k)
#define NT8 128       // K-tiles of 64 in mega GEMM

typedef __bf16 bf16_t;
typedef __bf16 bf16x8 __attribute__((ext_vector_type(8)));
typedef __bf16 bf16x4 __attribute__((ext_vector_type(4)));
typedef float  f32x4  __attribute__((ext_vector_type(4)));

__device__ __forceinline__ void gload_lds16(const void* g, void* l) {
    __builtin_amdgcn_global_load_lds((const __attribute__((address_space(1))) void*)g,
                                     (__attribute__((address_space(3))) void*)l, 16, 0, 0);
}

// ---------------------------------------------------------------------------
// x (C=8192, N=1024) fp32 -> xT (N, C) bf16, LDS-tiled transpose
__global__ __launch_bounds__(256) void transpose_cvt_x(const float* __restrict__ x,
                                                       bf16_t* __restrict__ xT) {
    __shared__ float t[32][33];
    const int n0 = blockIdx.x * 32, c0 = blockIdx.y * 32;
    const int tx = threadIdx.x, ty = threadIdx.y; // block (32,8)
    #pragma unroll
    for (int i = 0; i < 4; ++i)
        t[ty + i * 8][tx] = x[(size_t)(c0 + ty + i * 8) * NDIM + n0 + tx];
    __syncthreads();
    #pragma unroll
    for (int i = 0; i < 4; ++i)
        xT[(size_t)(n0 + ty + i * 8) * CDIM + c0 + tx] = (__bf16)t[tx][ty + i * 8];
}

// ---------------------------------------------------------------------------
// Mega-GEMM, 256x256 tile, BK=64, 8 waves, R6's 4-phase counted-vmcnt schedule.
// A is consumed as RAW FP32 (no pre-convert): tile t+1's A is issued at j0 as
// 8 inline-asm global_load_dwordx4 (invisible to the compiler scoreboard, so
// only OUR counted vmcnt orders them), cvt'd to bf16 and ds_write'n (swizzled)
// at j2 (half 0, after vmcnt(6)) and j3 (half 1, after vmcnt(2)).
// Steady-state ledger (entering tile t in-flight = {Bh0(t+1)}2):
//   j0: +Bh1(t+1)[2 gl_lds] +A(t+1)[8 asm]            (in-flight 12)
//   j2: +Bh0(t+2)[2]; vmcnt(6) drains Bh0/Bh1(t+1)+A0 -> write Ah0(t+1)
//   j3: vmcnt(2) drains A1 -> write Ah1(t+1); keeps {Bh0(t+2)}2  [invariant]
// B-path and all read/MMA geometry identical to the verified R6 kernel.
__global__ __launch_bounds__(512, 2) void mega_gemm8(
    const float* __restrict__ Wv, const float* __restrict__ Wq,
    const float* __restrict__ Wk, const bf16_t* __restrict__ Bx,
    bf16_t* __restrict__ v_out, float* __restrict__ q_out, float* __restrict__ k_out,
    const float* __restrict__ v_scale, const float* __restrict__ v_shift,
    const float* __restrict__ q_scale, const float* __restrict__ q_shift,
    const float* __restrict__ k_scale, const float* __restrict__ k_shift)
{
    __shared__ __align__(16) bf16_t Ld[65536];   // A[2][16384] | B[2][16384] @32768

    const int tid  = threadIdx.x;
    const int lane = tid & 63;
    const int wid  = tid >> 6;
    const int wr   = wid >> 2;        // 0..1
    const int wc   = wid & 3;         // 0..3

    // XCD-aware bijective swizzle (nwg = 160, %8 == 0; 20 tiles per XCD)
    const int lin  = blockIdx.y * 4 + blockIdx.x;
    const int tile = (lin & 7) * 20 + (lin >> 3);
    const int trow = tile >> 2;
    const int col0 = (tile & 3) * 256;

    const float* Ag; const float* s0; const float* s1; int arow, path;
    if (trow < 32)      { Ag = Wv; arow = trow * 256;        s0 = v_scale; s1 = v_shift; path = 0; }
    else if (trow < 36) { Ag = Wq; arow = trow * 256 - 8192; s0 = q_scale; s1 = q_shift; path = 1; }
    else                { Ag = Wk; arow = trow * 256 - 9216; s0 = k_scale; s1 = k_shift; path = 2; }

    // B staging (gload_lds): half-tile 128x64 bf16 = 16KB = 512thr x 2x16B
    const int ar0 = tid >> 3;                                  // row 0..63 in 64-chunk
    const int o0  = tid * 8;                                   // LDS elem offset
    const int csw = (((tid & 7) ^ ((tid >> 3) & 7)) << 3);     // pre-swizzled src col

    // A staging (asm reg): half-tile = 128 rows x 64 fp32; thread -> row tid>>2,
    // lin 16B-slots s0=(tid&3)*2, s0+1. Data for lin slot s comes from source
    // col 8*(s ^ (row&7)) (matches the XOR layout the read side expects).
    const int awrow = tid >> 2;            // 0..127
    const int asl0  = (tid & 3) * 2;
    const int asl1  = asl0 + 1;
    size_t aoff[2][4];
    #pragma unroll
    for (int h = 0; h < 2; ++h) {
        #pragma unroll
        for (int q = 0; q < 4; ++q) {
            const int sl = asl0 + (q >> 1);
            aoff[h][q] = (size_t)(arow + h * 128 + awrow) * CDIM
                       + 8 * (sl ^ (awrow & 7)) + (q & 1) * 4;
        }
    }

    // read geometry (identical to R6)
    const int lr   = lane & 15;
    const int hi8  = (lane >> 4) * 8;
    const int rsw  = (lane & 7) << 3;
    const int ck0  = hi8 ^ rsw;
    const int ck1  = (32 + hi8) ^ rsw;
    const int aRow = wr * 64 + lr;
    const int bRow = wc * 32 + lr;

    bf16x8 av[4][2];
    bf16x8 bv[2][2][2];
    f32x4  acc[2][2][4][2];
    f32x4  rA0[4], rA1[4];               // asm-load targets (constant-indexed)
    #pragma unroll
    for (int mh = 0; mh < 2; ++mh)
        #pragma unroll
        for (int nh = 0; nh < 2; ++nh)
            #pragma unroll
            for (int fi = 0; fi < 4; ++fi)
                #pragma unroll
                for (int fj = 0; fj < 2; ++fj)
                    acc[mh][nh][fi][fj] = (f32x4){0.f, 0.f, 0.f, 0.f};

#define STAGE_BH(BUF, H, KB) do {                                                             \
    gload_lds16(Bx + (size_t)(col0 + (H)*128 + ar0     ) * CDIM + (KB) + csw,                 \
                Ld + 32768 + (BUF)*16384 + (H)*8192 + o0);                                    \
    gload_lds16(Bx + (size_t)(col0 + (H)*128 + ar0 + 64) * CDIM + (KB) + csw,                 \
                Ld + 32768 + (BUF)*16384 + (H)*8192 + o0 + 4096);                             \
} while (0)

#define A_ISSUE(RA, H, KB) do {                                                               \
    _Pragma("unroll") for (int q = 0; q < 4; ++q)                                             \
        asm volatile("global_load_dwordx4 %0, %1, off"                                       \
            : "=v"(RA[q]) : "v"(Ag + aoff[(H)][q] + (KB)) : "memory");                        \
} while (0)

#define A_WRITE(RA, BUF, H) do {                                                              \
    bf16_t* wb_ = Ld + (BUF)*16384 + (H)*8192 + awrow * 64;                                   \
    bf16x8 w0_ = { (__bf16)RA[0][0], (__bf16)RA[0][1], (__bf16)RA[0][2], (__bf16)RA[0][3],    \
                   (__bf16)RA[1][0], (__bf16)RA[1][1], (__bf16)RA[1][2], (__bf16)RA[1][3] };  \
    bf16x8 w1_ = { (__bf16)RA[2][0], (__bf16)RA[2][1], (__bf16)RA[2][2], (__bf16)RA[2][3],    \
                   (__bf16)RA[3][0], (__bf16)RA[3][1], (__bf16)RA[3][2], (__bf16)RA[3][3] };  \
    *(bf16x8*)(wb_ + asl0 * 8) = w0_;                                                         \
    *(bf16x8*)(wb_ + asl1 * 8) = w1_;                                                         \
} while (0)

#define RD_A(BUF, MH) do {                                                                    \
    _Pragma("unroll") for (int fi = 0; fi < 4; ++fi) {                                        \
        av[fi][0] = *(const bf16x8*)(Ld + (BUF)*16384 + ((MH)*128 + aRow + fi*16)*64 + ck0);  \
        av[fi][1] = *(const bf16x8*)(Ld + (BUF)*16384 + ((MH)*128 + aRow + fi*16)*64 + ck1);  \
    }                                                                                         \
} while (0)

#define RD_B(BUF, NH) do {                                                                    \
    _Pragma("unroll") for (int fj = 0; fj < 2; ++fj) {                                        \
        bv[NH][fj][0] = *(const bf16x8*)(Ld + 32768 + (BUF)*16384 +                           \
                                         ((NH)*128 + bRow + fj*16)*64 + ck0);                 \
        bv[NH][fj][1] = *(const bf16x8*)(Ld + 32768 + (BUF)*16384 +                           \
                                         ((NH)*128 + bRow + fj*16)*64 + ck1);                 \
    }                                                                                         \
} while (0)

#define MMA(MH, NH) do {                                                                      \
    __builtin_amdgcn_s_setprio(1);                                                            \
    _Pragma("unroll") for (int kk = 0; kk < 2; ++kk)                                          \
        _Pragma("unroll") for (int fi = 0; fi < 4; ++fi)                                      \
            _Pragma("unroll") for (int fj = 0; fj < 2; ++fj)                                  \
                acc[MH][NH][fi][fj] = __builtin_amdgcn_mfma_f32_16x16x32_bf16(                \
                    av[fi][kk], bv[NH][fj][kk], acc[MH][NH][fi][fj], 0, 0, 0);                \
    __builtin_amdgcn_s_setprio(0);                                                            \
} while (0)

#define LGKM0 do { asm volatile("s_waitcnt lgkmcnt(0)" ::: "memory");                         \
                   __builtin_amdgcn_sched_barrier(0); } while (0)
#define VM(N) do { asm volatile("s_waitcnt vmcnt(" #N ")" ::: "memory");                      \
                   __builtin_amdgcn_sched_barrier(0); } while (0)
#define BAR   __builtin_amdgcn_s_barrier()

    // ---- prologue: A(0) via regs, B(0)+Bh0(1) via gload_lds
    A_ISSUE(rA0, 0, 0);             // A0(0) [4]
    A_ISSUE(rA1, 1, 0);             // A1(0) [4]
    STAGE_BH(0, 0, 0);              // Bh0(0) [2]
    STAGE_BH(0, 1, 0);              // Bh1(0) [2]
    STAGE_BH(1, 0, 64);             // Bh0(1) [2]
    VM(6);                          // drain A(0)8 ; keep B(0)4 + Bh0(1)2
    A_WRITE(rA0, 0, 0);
    A_WRITE(rA1, 0, 1);
    VM(2);                          // drain B(0) ; keep Bh0(1)2  [invariant]
    LGKM0;
    BAR;

// steady K-tile (0 <= T <= NT8-3)
#define KTILE_C(BUF, T) do {                                                                  \
    /* j0 */                                                                                  \
    RD_A(BUF, 0); RD_B(BUF, 0);                                                               \
    STAGE_BH((BUF)^1, 1, ((T)+1)*64);                                                         \
    A_ISSUE(rA0, 0, ((T)+1)*64);                                                              \
    A_ISSUE(rA1, 1, ((T)+1)*64);                                                              \
    BAR; LGKM0; MMA(0, 0); BAR;                                                               \
    /* j1 */                                                                                  \
    RD_B(BUF, 1);                                                                             \
    BAR; LGKM0; MMA(0, 1); BAR;                                                               \
    /* j2 */                                                                                  \
    RD_A(BUF, 1);                                                                             \
    STAGE_BH(BUF, 0, ((T)+2)*64);                                                             \
    VM(6);                                                                                    \
    A_WRITE(rA0, (BUF)^1, 0);                                                                 \
    BAR; LGKM0; MMA(1, 1); BAR;                                                               \
    /* j3 */                                                                                  \
    VM(2);                                                                                    \
    A_WRITE(rA1, (BUF)^1, 1);                                                                 \
    BAR; LGKM0; MMA(1, 0); BAR;                                                               \
} while (0)

    for (int t = 0; t < NT8 - 2; t += 2) {
        KTILE_C(0, t);
        KTILE_C(1, t + 1);
    }
    // T = NT8-2 (buf 0): stage tile 127's B-half1 + A; no t+2 staging
    {
        RD_A(0, 0); RD_B(0, 0);
        STAGE_BH(1, 1, (NT8 - 1) * 64);
        A_ISSUE(rA0, 0, (NT8 - 1) * 64);
        A_ISSUE(rA1, 1, (NT8 - 1) * 64);
        BAR; LGKM0; MMA(0, 0); BAR;
        RD_B(0, 1);
        BAR; LGKM0; MMA(0, 1); BAR;
        RD_A(0, 1);
        VM(4);                       // drain Bh0/Bh1(127)+A0(127); keep A1(127)4
        A_WRITE(rA0, 1, 0);
        BAR; LGKM0; MMA(1, 1); BAR;
        VM(0);                       // drain A1(127)
        A_WRITE(rA1, 1, 1);
        BAR; LGKM0; MMA(1, 0); BAR;
    }
    // T = NT8-1 (buf 1): everything resident
    {
        RD_A(1, 0); RD_B(1, 0);
        BAR; LGKM0; MMA(0, 0); BAR;
        RD_B(1, 1);
        BAR; LGKM0; MMA(0, 1); BAR;
        RD_A(1, 1);
        BAR; LGKM0; MMA(1, 1); BAR;
        LGKM0; MMA(1, 0);
    }

#undef KTILE_C
#undef BAR
#undef VM
#undef LGKM0
#undef MMA
#undef RD_B
#undef RD_A
#undef A_WRITE
#undef A_ISSUE
#undef STAGE_BH

    // epilogue: C/D layout col = lane&15, row = (lane>>4)*4 + r
    const int cq = (lane >> 4) * 4;
    #pragma unroll
    for (int mh = 0; mh < 2; ++mh) {
        #pragma unroll
        for (int nh = 0; nh < 2; ++nh) {
            #pragma unroll
            for (int fi = 0; fi < 4; ++fi) {
                #pragma unroll
                for (int fj = 0; fj < 2; ++fj) {
                    const int j = col0 + nh * 128 + wc * 32 + fj * 16 + lr;
                    #pragma unroll
                    for (int r = 0; r < 4; ++r) {
                        const int il = arow + mh * 128 + wr * 64 + fi * 16 + cq + r;
                        float vv = acc[mh][nh][fi][fj][r] * s0[il] + s1[il];
                        if (path == 0)      v_out[(size_t)il * NDIM + j] = (__bf16)vv;
                        else if (path == 1) q_out[(size_t)il * NDIM + j] = vv;
                        else                k_out[(size_t)il * NDIM + j] = vv;
                    }
                }
            }
        }
    }
}

// ---------------------------------------------------------------------------
// bt-GEMM: C[i,j] = sum_k A[i,k] * B[j,k]. XCD-swizzled xy grid; optional
// split-K via gridDim.z (each z writes its own partial plane C + z*M*N).
// EPI: 2 = v*(1/1023)/(e0[j]*e1[j])  -> ppmcc partial
//      3 = gs[0]*v + e0[i*N+j]       -> gamma*out + x
template <int EPI, typename OutT>
__global__ __launch_bounds__(256) void gemm_bt(
    const bf16_t* __restrict__ A, const bf16_t* __restrict__ B,
    OutT* __restrict__ C, int M, int N, int K,
    const float* __restrict__ e0, const float* __restrict__ e1,
    const float* __restrict__ gs)
{
    const int gx = gridDim.x;
    const int nwg = gx * gridDim.y;
    const int lin = blockIdx.y * gx + blockIdx.x;
    int tile = lin;
    if ((nwg & 7) == 0) tile = (lin & 7) * (nwg >> 3) + (lin >> 3);
    const int row0 = (tile / gx) * 128;
    const int col0 = (tile % gx) * 128;

    const int Ks  = K / gridDim.z;
    const int kb0 = blockIdx.z * Ks;
    const int kb1 = kb0 + Ks;
    OutT* Cz = C + (size_t)blockIdx.z * M * N;

    const int tid = threadIdx.x;
    __shared__ __align__(16) bf16_t As[2 * 4096];
    __shared__ __align__(16) bf16_t Bs[2 * 4096];

    const int lane = tid & 63;
    const int w    = tid >> 6;
    const int wm   = (w >> 1) * 64;
    const int wn   = (w & 1) * 64;
    const int lr   = lane & 15;
    const int kg   = (lane >> 4) * 8;

    f32x4 acc[4][4];
    #pragma unroll
    for (int a_ = 0; a_ < 4; ++a_)
        #pragma unroll
        for (int b_ = 0; b_ < 4; ++b_)
            acc[a_][b_] = (f32x4){0.f, 0.f, 0.f, 0.f};

    const int eA = tid * 8;
    const int eB = (256 + tid) * 8;
    const int rA = eA >> 5, cA = eA & 31;
    const int rB = eB >> 5, cB = eB & 31;

#define BT_STAGE(buf, kb)                                                       \
    do {                                                                        \
        gload_lds16(A + (size_t)(row0 + rA) * K + (kb) + cA, As + (buf)*4096 + eA); \
        gload_lds16(A + (size_t)(row0 + rB) * K + (kb) + cB, As + (buf)*4096 + eB); \
        gload_lds16(B + (size_t)(col0 + rA) * K + (kb) + cA, Bs + (buf)*4096 + eA); \
        gload_lds16(B + (size_t)(col0 + rB) * K + (kb) + cB, Bs + (buf)*4096 + eB); \
    } while (0)

    BT_STAGE(0, kb0);
    __syncthreads();
    int cur = 0;
    for (int kb = kb0; kb < kb1; kb += 32) {
        if (kb + 32 < kb1) BT_STAGE(cur ^ 1, kb + 32);
        const bf16_t* Ac = As + cur * 4096;
        const bf16_t* Bc = Bs + cur * 4096;

        bf16x8 av[4], bv[4];
        #pragma unroll
        for (int mi = 0; mi < 4; ++mi)
            av[mi] = *(const bf16x8*)(Ac + (wm + mi * 16 + lr) * 32 + kg);
        #pragma unroll
        for (int ni = 0; ni < 4; ++ni)
            bv[ni] = *(const bf16x8*)(Bc + (wn + ni * 16 + lr) * 32 + kg);

        #pragma unroll
        for (int mi = 0; mi < 4; ++mi)
            #pragma unroll
            for (int ni = 0; ni < 4; ++ni)
                acc[mi][ni] = __builtin_amdgcn_mfma_f32_16x16x32_bf16(
                    av[mi], bv[ni], acc[mi][ni], 0, 0, 0);
        __syncthreads();
        cur ^= 1;
    }
#undef BT_STAGE

    float g = 0.f;
    if (EPI == 3) g = gs[0];
    const int cr = (lane >> 4) * 4;
    #pragma unroll
    for (int mi = 0; mi < 4; ++mi) {
        #pragma unroll
        for (int ni = 0; ni < 4; ++ni) {
            const int j = col0 + wn + ni * 16 + lr;
            float s0 = 0.f, s1 = 0.f;
            if (EPI == 2) { s0 = e0[j]; s1 = e1[j]; }
            #pragma unroll
            for (int r = 0; r < 4; ++r) {
                const int i = row0 + wm + mi * 16 + cr + r;
                float v = acc[mi][ni][r];
                if (EPI == 2)      v = v * (1.0f / 1023.0f) / (s0 * s1);
                else if (EPI == 3) v = g * v + e0[(size_t)i * N + j];
                Cz[(size_t)i * N + j] = (OutT)v;
            }
        }
    }
}

// ---------------------------------------------------------------------------
// Row mean/std (ddof=0) of q_on / k_on (each 1024 x 1024 fp32). One wave/row.
__global__ __launch_bounds__(256) void rowstats(
    const float* __restrict__ Q, const float* __restrict__ Km,
    float* __restrict__ qmean, float* __restrict__ qstd,
    float* __restrict__ kmean, float* __restrict__ kstd)
{
    const int wid  = blockIdx.x * 4 + (threadIdx.x >> 6);
    const int lane = threadIdx.x & 63;
    const float* src = (wid < 1024) ? (Q + (size_t)wid * NDIM)
                                    : (Km + (size_t)(wid - 1024) * NDIM);
    float s = 0.f, s2 = 0.f;
    #pragma unroll
    for (int p = 0; p < 4; ++p) {
        float4 v = *(const float4*)(src + p * 256 + lane * 4);
        s  += v.x + v.y + v.z + v.w;
        s2 += v.x * v.x + v.y * v.y + v.z * v.z + v.w * v.w;
    }
    #pragma unroll
    for (int o = 32; o; o >>= 1) { s += __shfl_xor(s, o); s2 += __shfl_xor(s2, o); }
    if (lane == 0) {
        float m   = s / 1024.f;
        float var = fmaxf(s2 / 1024.f - m * m, 0.f);
        if (wid < 1024) { qmean[wid] = m; qstd[wid] = sqrtf(var); }
        else            { kmean[wid - 1024] = m; kstd[wid - 1024] = sqrtf(var); }
    }
}

// ---------------------------------------------------------------------------
// Center by row mean, transpose (o,n)->(n,o), convert bf16. z selects q/k.
__global__ __launch_bounds__(256) void center_tr(
    const float* __restrict__ Q, const float* __restrict__ qmu, bf16_t* __restrict__ qc,
    const float* __restrict__ Km, const float* __restrict__ kmu, bf16_t* __restrict__ kc)
{
    __shared__ float t[32][33];
    const float* M  = blockIdx.z ? Km  : Q;
    const float* mu = blockIdx.z ? kmu : qmu;
    bf16_t* O       = blockIdx.z ? kc  : qc;
    const int o0 = blockIdx.y * 32, n0 = blockIdx.x * 32;
    const int tx = threadIdx.x, ty = threadIdx.y; // block (32,8)
    #pragma unroll
    for (int i = 0; i < 4; ++i) {
        const int o = o0 + ty + i * 8;
        t[ty + i * 8][tx] = M[(size_t)o * NDIM + n0 + tx] - mu[o];
    }
    __syncthreads();
    #pragma unroll
    for (int i = 0; i < 4; ++i)
        O[(size_t)(n0 + ty + i * 8) * C8D + o0 + tx] = (__bf16)t[tx][ty + i * 8];
}

// ---------------------------------------------------------------------------
// Row softmax over the sum of 4 split-K partial P planes -> bf16 A0.
__global__ __launch_bounds__(256) void softmax_rows(const float* __restrict__ P,
                                                    bf16_t* __restrict__ O) {
    const int row = blockIdx.x;
    const int tid = threadIdx.x;
    const size_t PL = (size_t)NDIM * NDIM / 4;   // plane size in float4 units
    const size_t u  = (size_t)row * (NDIM / 4) + tid;
    const float4* B = (const float4*)P;
    float4 p0 = B[u], p1 = B[u + PL], p2 = B[u + 2 * PL], p3 = B[u + 3 * PL];
    float4 v = { p0.x + p1.x + p2.x + p3.x, p0.y + p1.y + p2.y + p3.y,
                 p0.z + p1.z + p2.z + p3.z, p0.w + p1.w + p2.w + p3.w };
    float mx = fmaxf(fmaxf(v.x, v.y), fmaxf(v.z, v.w));
    #pragma unroll
    for (int o = 32; o; o >>= 1) mx = fmaxf(mx, __shfl_xor(mx, o));
    __shared__ float red[8];
    const int w = tid >> 6, lane = tid & 63;
    if (lane == 0) red[w] = mx;
    __syncthreads();
    mx = fmaxf(fmaxf(red[0], red[1]), fmaxf(red[2], red[3]));
    float e0 = __expf(v.x - mx), e1 = __expf(v.y - mx);
    float e2 = __expf(v.z - mx), e3 = __expf(v.w - mx);
    float s = e0 + e1 + e2 + e3;
    #pragma unroll
    for (int o = 32; o; o >>= 1) s += __shfl_xor(s, o);
    if (lane == 0) red[4 + w] = s;
    __syncthreads();
    s = red[4] + red[5] + red[6] + red[7];
    const float inv = 1.0f / s;
    bf16x4 o4 = { (__bf16)(e0 * inv), (__bf16)(e1 * inv),
                  (__bf16)(e2 * inv), (__bf16)(e3 * inv) };
    ((bf16x4*)(O + (size_t)row * NDIM))[tid] = o4;
}

// ---------------------------------------------------------------------------
extern "C" void kernel_launch(void* const* d_in, const int* in_sizes, int n_in,
                              void* d_out, int out_size, void* d_ws, size_t ws_size,
                              hipStream_t stream)
{
    const float* x       = (const float*)d_in[0];
    const float* Wq      = (const float*)d_in[1];
    const float* Wk      = (const float*)d_in[2];
    const float* Wv      = (const float*)d_in[3];
    const float* q_scale = (const float*)d_in[4];
    const float* q_shift = (const float*)d_in[5];
    const float* k_scale = (const float*)d_in[6];
    const float* k_shift = (const float*)d_in[7];
    const float* v_scale = (const float*)d_in[8];
    const float* v_shift = (const float*)d_in[9];
    const float* gamma   = (const float*)d_in[10];
    float* out = (float*)d_out;

    // workspace layout (~65 MB)
    char* w = (char*)d_ws;
    bf16_t* xT   = (bf16_t*)w; w += (size_t)NDIM * CDIM * 2;
    bf16_t* v_b  = (bf16_t*)w; w += (size_t)CDIM * NDIM * 2;
    float*  q_on = (float*) w; w += (size_t)C8D * NDIM * 4;
    float*  k_on = (float*) w; w += (size_t)C8D * NDIM * 4;
    float*  P    = (float*) w; w += (size_t)4 * NDIM * NDIM * 4;  // 4 split-K planes
    bf16_t* qc   = (bf16_t*)w; w += (size_t)NDIM * C8D * 2;
    bf16_t* kc   = (bf16_t*)w; w += (size_t)NDIM * C8D * 2;
    bf16_t* A0   = (bf16_t*)w; w += (size_t)NDIM * NDIM * 2;
    float*  qmean = (float*)w; w += C8D * 4;
    float*  qstd  = (float*)w; w += C8D * 4;
    float*  kmean = (float*)w; w += C8D * 4;
    float*  kstd  = (float*)w; w += C8D * 4;

    // 1. x transpose + bf16 (weights are consumed fp32 directly by mega)
    transpose_cvt_x<<<dim3(NDIM / 32, CDIM / 32), dim3(32, 8), 0, stream>>>(x, xT);

    // 2. mega-GEMM, 256^2 4-phase counted-vmcnt pipeline, asm-reg-staged fp32 A
    mega_gemm8<<<dim3(4, MSTACK / 256), 512, 0, stream>>>(
        Wv, Wq, Wk, xT, v_b, q_on, k_on,
        v_scale, v_shift, q_scale, q_shift, k_scale, k_shift);

    // 3. row stats of q_on / k_on (2048 waves)
    rowstats<<<512, 256, 0, stream>>>(q_on, k_on, qmean, qstd, kmean, kstd);

    // 4. center + transpose + bf16
    center_tr<<<dim3(32, 32, 2), dim3(32, 8), 0, stream>>>(
        q_on, qmean, qc, k_on, kmean, kc);

    // 5. P[z] = (qc . kc^T)_z / 1023 / (qstd[j] * kstd[j]), split-K x4 (256 blocks)
    gemm_bt<2, float><<<dim3(NDIM / 128, NDIM / 128, 4), 256, 0, stream>>>(
        qc, kc, P, NDIM, NDIM, C8D, qstd, kstd, nullptr);

    // 6. row softmax over summed partials -> A0 (bf16)
    softmax_rows<<<NDIM, 256, 0, stream>>>(P, A0);

    // 7. out = gamma * (v . A0^T) + x
    gemm_bt<3, float><<<dim3(NDIM / 128, CDIM / 128, 1), 256, 0, stream>>>(
        v_b, A0, out, CDIM, NDIM, NDIM, x, x, gamma);
}

// Round 9
// 371.027 us; speedup vs baseline: 1.5028x; 1.5028x over previous
//
#include <hip/hip_runtime.h>
#include <cstdint>
#include <cstddef>

// Problem dims (fixed)
#define CDIM 8192
#define NDIM 1024   // H*W
#define C8D  1024
#define MSTACK 10240  // 8192 (v) + 1024 (q) + 1024 (k)
#define NT8 128       // K-tiles of 64 in mega GEMM

typedef __bf16 bf16_t;
typedef __bf16 bf16x8 __attribute__((ext_vector_type(8)));
typedef __bf16 bf16x4 __attribute__((ext_vector_type(4)));
typedef float  f32x4  __attribute__((ext_vector_type(4)));

__device__ __forceinline__ void gload_lds16(const void* g, void* l) {
    __builtin_amdgcn_global_load_lds((const __attribute__((address_space(1))) void*)g,
                                     (__attribute__((address_space(3))) void*)l, 16, 0, 0);
}

// ---------------------------------------------------------------------------
// x (C=8192, N=1024) fp32 -> xT (N, C) bf16, LDS-tiled transpose
__global__ __launch_bounds__(256) void transpose_cvt_x(const float* __restrict__ x,
                                                       bf16_t* __restrict__ xT) {
    __shared__ float t[32][33];
    const int n0 = blockIdx.x * 32, c0 = blockIdx.y * 32;
    const int tx = threadIdx.x, ty = threadIdx.y; // block (32,8)
    #pragma unroll
    for (int i = 0; i < 4; ++i)
        t[ty + i * 8][tx] = x[(size_t)(c0 + ty + i * 8) * NDIM + n0 + tx];
    __syncthreads();
    #pragma unroll
    for (int i = 0; i < 4; ++i)
        xT[(size_t)(n0 + ty + i * 8) * CDIM + c0 + tx] = (__bf16)t[tx][ty + i * 8];
}

// ---------------------------------------------------------------------------
// Mega-GEMM, 256x256 tile, BK=64, 8 waves, R6's 4-phase counted-vmcnt schedule,
// fused fp32 A-path. Fixes vs R7/R8: (a) __launch_bounds__(512,1) — LDS already
// caps at 1 block/CU, so allow up to 256 VGPR (no spills from reg staging);
// (b) A staging mirrors the B gload_lds geometry: thread=(row tid>>3, grp
// tid&7), SOURCE col XOR-pre-swizzled, LDS write is one linear bf16x8 at
// tid*8 per 64-row issue — conflict-free ds_write.
// Ledger (entering tile t: in-flight {Bh0(t+1)}2):
//   j0: +Bh1(t+1)[2 gl_lds] +A(t+1)[8 asm dwordx4]    (12)
//   j2: +Bh0(t+2)[2]; vmcnt(6) drains B(t+1)4+A_H0 4  -> write Ah0(t+1)
//   j3: vmcnt(2) drains A_H1 4                        -> write Ah1(t+1)
__global__ __launch_bounds__(512, 1) void mega_gemm8(
    const float* __restrict__ Wv, const float* __restrict__ Wq,
    const float* __restrict__ Wk, const bf16_t* __restrict__ Bx,
    bf16_t* __restrict__ v_out, float* __restrict__ q_out, float* __restrict__ k_out,
    const float* __restrict__ v_scale, const float* __restrict__ v_shift,
    const float* __restrict__ q_scale, const float* __restrict__ q_shift,
    const float* __restrict__ k_scale, const float* __restrict__ k_shift)
{
    __shared__ __align__(16) bf16_t Ld[65536];   // A[2][16384] | B[2][16384] @32768

    const int tid  = threadIdx.x;
    const int lane = tid & 63;
    const int wid  = tid >> 6;
    const int wr   = wid >> 2;        // 0..1
    const int wc   = wid & 3;         // 0..3

    // XCD-aware bijective swizzle (nwg = 160, %8 == 0; 20 tiles per XCD)
    const int lin  = blockIdx.y * 4 + blockIdx.x;
    const int tile = (lin & 7) * 20 + (lin >> 3);
    const int trow = tile >> 2;
    const int col0 = (tile & 3) * 256;

    const float* Ag; const float* s0; const float* s1; int arow, path;
    if (trow < 32)      { Ag = Wv; arow = trow * 256;        s0 = v_scale; s1 = v_shift; path = 0; }
    else if (trow < 36) { Ag = Wq; arow = trow * 256 - 8192; s0 = q_scale; s1 = q_shift; path = 1; }
    else                { Ag = Wk; arow = trow * 256 - 9216; s0 = k_scale; s1 = k_shift; path = 2; }

    // B staging (gload_lds): half-tile 128x64 bf16 = 16KB = 512thr x 2x16B
    const int ar0 = tid >> 3;                                  // row 0..63 in 64-chunk
    const int o0  = tid * 8;                                   // LDS elem offset
    const int csw = (((tid & 7) ^ ((tid >> 3) & 7)) << 3);     // pre-swizzled src col

    // A staging (asm reg->cvt->linear ds_write): same (row,grp) map as B.
    // Source col pre-XOR'd so LDS linear layout == B's swizzled convention.
    const float* aP0 = Ag + (size_t)(arow + ar0) * CDIM + csw;   // H0, rows 0-63
    const float* aP1 = aP0 + (size_t)64  * CDIM;                 // H0, rows 64-127
    const float* aP2 = aP0 + (size_t)128 * CDIM;                 // H1, rows 0-63
    const float* aP3 = aP0 + (size_t)192 * CDIM;                 // H1, rows 64-127

    // read geometry (identical to R6)
    const int lr   = lane & 15;
    const int hi8  = (lane >> 4) * 8;
    const int rsw  = (lane & 7) << 3;
    const int ck0  = hi8 ^ rsw;
    const int ck1  = (32 + hi8) ^ rsw;
    const int aRow = wr * 64 + lr;
    const int bRow = wc * 32 + lr;

    bf16x8 av[4][2];
    bf16x8 bv[2][2][2];
    f32x4  acc[2][2][4][2];
    f32x4  rA0[4], rA1[4];     // A reg windows: [0,1]=rows 0-63, [2,3]=rows 64-127
    #pragma unroll
    for (int mh = 0; mh < 2; ++mh)
        #pragma unroll
        for (int nh = 0; nh < 2; ++nh)
            #pragma unroll
            for (int fi = 0; fi < 4; ++fi)
                #pragma unroll
                for (int fj = 0; fj < 2; ++fj)
                    acc[mh][nh][fi][fj] = (f32x4){0.f, 0.f, 0.f, 0.f};

#define STAGE_BH(BUF, H, KB) do {                                                             \
    gload_lds16(Bx + (size_t)(col0 + (H)*128 + ar0     ) * CDIM + (KB) + csw,                 \
                Ld + 32768 + (BUF)*16384 + (H)*8192 + o0);                                    \
    gload_lds16(Bx + (size_t)(col0 + (H)*128 + ar0 + 64) * CDIM + (KB) + csw,                 \
                Ld + 32768 + (BUF)*16384 + (H)*8192 + o0 + 4096);                             \
} while (0)

// issue one A half-tile (H selects aP0/aP1 vs aP2/aP3): 4 x global_load_dwordx4
#define A_ISSUE(RA, PA, PB, KB) do {                                                          \
    asm volatile("global_load_dwordx4 %0, %1, off"           : "=v"(RA[0]) : "v"((PA)+(KB)));\
    asm volatile("global_load_dwordx4 %0, %1, off offset:16" : "=v"(RA[1]) : "v"((PA)+(KB)));\
    asm volatile("global_load_dwordx4 %0, %1, off"           : "=v"(RA[2]) : "v"((PB)+(KB)));\
    asm volatile("global_load_dwordx4 %0, %1, off offset:16" : "=v"(RA[3]) : "v"((PB)+(KB)));\
} while (0)

// cvt + linear conflict-free ds_write of one A half-tile
#define A_WRITE(RA, BUF, H) do {                                                              \
    bf16_t* wb_ = Ld + (BUF)*16384 + (H)*8192;                                                \
    bf16x8 w0_ = { (__bf16)RA[0][0], (__bf16)RA[0][1], (__bf16)RA[0][2], (__bf16)RA[0][3],    \
                   (__bf16)RA[1][0], (__bf16)RA[1][1], (__bf16)RA[1][2], (__bf16)RA[1][3] };  \
    bf16x8 w1_ = { (__bf16)RA[2][0], (__bf16)RA[2][1], (__bf16)RA[2][2], (__bf16)RA[2][3],    \
                   (__bf16)RA[3][0], (__bf16)RA[3][1], (__bf16)RA[3][2], (__bf16)RA[3][3] };  \
    *(bf16x8*)(wb_ + o0)        = w0_;                                                        \
    *(bf16x8*)(wb_ + o0 + 4096) = w1_;                                                        \
} while (0)

#define RD_A(BUF, MH) do {                                                                    \
    _Pragma("unroll") for (int fi = 0; fi < 4; ++fi) {                                        \
        av[fi][0] = *(const bf16x8*)(Ld + (BUF)*16384 + ((MH)*128 + aRow + fi*16)*64 + ck0);  \
        av[fi][1] = *(const bf16x8*)(Ld + (BUF)*16384 + ((MH)*128 + aRow + fi*16)*64 + ck1);  \
    }                                                                                         \
} while (0)

#define RD_B(BUF, NH) do {                                                                    \
    _Pragma("unroll") for (int fj = 0; fj < 2; ++fj) {                                        \
        bv[NH][fj][0] = *(const bf16x8*)(Ld + 32768 + (BUF)*16384 +                           \
                                         ((NH)*128 + bRow + fj*16)*64 + ck0);                 \
        bv[NH][fj][1] = *(const bf16x8*)(Ld + 32768 + (BUF)*16384 +                           \
                                         ((NH)*128 + bRow + fj*16)*64 + ck1);                 \
    }                                                                                         \
} while (0)

#define MMA(MH, NH) do {                                                                      \
    __builtin_amdgcn_s_setprio(1);                                                            \
    _Pragma("unroll") for (int kk = 0; kk < 2; ++kk)                                          \
        _Pragma("unroll") for (int fi = 0; fi < 4; ++fi)                                      \
            _Pragma("unroll") for (int fj = 0; fj < 2; ++fj)                                  \
                acc[MH][NH][fi][fj] = __builtin_amdgcn_mfma_f32_16x16x32_bf16(                \
                    av[fi][kk], bv[NH][fj][kk], acc[MH][NH][fi][fj], 0, 0, 0);                \
    __builtin_amdgcn_s_setprio(0);                                                            \
} while (0)

#define LGKM0 do { asm volatile("s_waitcnt lgkmcnt(0)" ::: "memory");                         \
                   __builtin_amdgcn_sched_barrier(0); } while (0)
#define VM(N) do { asm volatile("s_waitcnt vmcnt(" #N ")" ::: "memory");                      \
                   __builtin_amdgcn_sched_barrier(0); } while (0)
#define BAR   __builtin_amdgcn_s_barrier()

    // ---- prologue
    A_ISSUE(rA0, aP0, aP1, 0);      // A H0(0) [4]
    A_ISSUE(rA1, aP2, aP3, 0);      // A H1(0) [4]
    STAGE_BH(0, 0, 0);              // Bh0(0) [2]
    STAGE_BH(0, 1, 0);              // Bh1(0) [2]
    STAGE_BH(1, 0, 64);             // Bh0(1) [2]
    VM(6);                          // drain A(0)8 ; keep B(0)4 + Bh0(1)2
    A_WRITE(rA0, 0, 0);
    A_WRITE(rA1, 0, 1);
    VM(2);                          // drain B(0) ; keep Bh0(1)2  [invariant]
    LGKM0;
    BAR;

// steady K-tile (0 <= T <= NT8-3)
#define KTILE_C(BUF, T) do {                                                                  \
    /* j0 */                                                                                  \
    RD_A(BUF, 0); RD_B(BUF, 0);                                                               \
    STAGE_BH((BUF)^1, 1, ((T)+1)*64);                                                         \
    A_ISSUE(rA0, aP0, aP1, ((T)+1)*64);                                                       \
    A_ISSUE(rA1, aP2, aP3, ((T)+1)*64);                                                       \
    BAR; LGKM0; MMA(0, 0); BAR;                                                               \
    /* j1 */                                                                                  \
    RD_B(BUF, 1);                                                                             \
    BAR; LGKM0; MMA(0, 1); BAR;                                                               \
    /* j2 */                                                                                  \
    RD_A(BUF, 1);                                                                             \
    STAGE_BH(BUF, 0, ((T)+2)*64);                                                             \
    VM(6);                                                                                    \
    A_WRITE(rA0, (BUF)^1, 0);                                                                 \
    BAR; LGKM0; MMA(1, 1); BAR;                                                               \
    /* j3 */                                                                                  \
    VM(2);                                                                                    \
    A_WRITE(rA1, (BUF)^1, 1);                                                                 \
    BAR; LGKM0; MMA(1, 0); BAR;                                                               \
} while (0)

    for (int t = 0; t < NT8 - 2; t += 2) {
        KTILE_C(0, t);
        KTILE_C(1, t + 1);
    }
    // T = NT8-2 (buf 0): stage tile 127's Bh1 + A; no t+2 staging
    {
        RD_A(0, 0); RD_B(0, 0);
        STAGE_BH(1, 1, (NT8 - 1) * 64);
        A_ISSUE(rA0, aP0, aP1, (NT8 - 1) * 64);
        A_ISSUE(rA1, aP2, aP3, (NT8 - 1) * 64);
        BAR; LGKM0; MMA(0, 0); BAR;
        RD_B(0, 1);
        BAR; LGKM0; MMA(0, 1); BAR;
        RD_A(0, 1);
        VM(4);                       // drain Bh0/Bh1(127)+A_H0(127); keep A_H1 4
        A_WRITE(rA0, 1, 0);
        BAR; LGKM0; MMA(1, 1); BAR;
        VM(0);                       // drain A_H1(127)
        A_WRITE(rA1, 1, 1);
        BAR; LGKM0; MMA(1, 0); BAR;
    }
    // T = NT8-1 (buf 1): everything resident
    {
        RD_A(1, 0); RD_B(1, 0);
        BAR; LGKM0; MMA(0, 0); BAR;
        RD_B(1, 1);
        BAR; LGKM0; MMA(0, 1); BAR;
        RD_A(1, 1);
        BAR; LGKM0; MMA(1, 1); BAR;
        LGKM0; MMA(1, 0);
    }

#undef KTILE_C
#undef BAR
#undef VM
#undef LGKM0
#undef MMA
#undef RD_B
#undef RD_A
#undef A_WRITE
#undef A_ISSUE
#undef STAGE_BH

    // epilogue: C/D layout col = lane&15, row = (lane>>4)*4 + r
    const int cq = (lane >> 4) * 4;
    #pragma unroll
    for (int mh = 0; mh < 2; ++mh) {
        #pragma unroll
        for (int nh = 0; nh < 2; ++nh) {
            #pragma unroll
            for (int fi = 0; fi < 4; ++fi) {
                #pragma unroll
                for (int fj = 0; fj < 2; ++fj) {
                    const int j = col0 + nh * 128 + wc * 32 + fj * 16 + lr;
                    #pragma unroll
                    for (int r = 0; r < 4; ++r) {
                        const int il = arow + mh * 128 + wr * 64 + fi * 16 + cq + r;
                        float vv = acc[mh][nh][fi][fj][r] * s0[il] + s1[il];
                        if (path == 0)      v_out[(size_t)il * NDIM + j] = (__bf16)vv;
                        else if (path == 1) q_out[(size_t)il * NDIM + j] = vv;
                        else                k_out[(size_t)il * NDIM + j] = vv;
                    }
                }
            }
        }
    }
}

// ---------------------------------------------------------------------------
// bt-GEMM: C[i,j] = sum_k A[i,k] * B[j,k]. XCD-swizzled xy grid; optional
// split-K via gridDim.z (each z writes its own partial plane C + z*M*N).
// EPI: 2 = v*(1/1023)/(e0[j]*e1[j])  -> ppmcc partial
//      3 = gs[0]*v + e0[i*N+j]       -> gamma*out + x
template <int EPI, typename OutT>
__global__ __launch_bounds__(256) void gemm_bt(
    const bf16_t* __restrict__ A, const bf16_t* __restrict__ B,
    OutT* __restrict__ C, int M, int N, int K,
    const float* __restrict__ e0, const float* __restrict__ e1,
    const float* __restrict__ gs)
{
    const int gx = gridDim.x;
    const int nwg = gx * gridDim.y;
    const int lin = blockIdx.y * gx + blockIdx.x;
    int tile = lin;
    if ((nwg & 7) == 0) tile = (lin & 7) * (nwg >> 3) + (lin >> 3);
    const int row0 = (tile / gx) * 128;
    const int col0 = (tile % gx) * 128;

    const int Ks  = K / gridDim.z;
    const int kb0 = blockIdx.z * Ks;
    const int kb1 = kb0 + Ks;
    OutT* Cz = C + (size_t)blockIdx.z * M * N;

    const int tid = threadIdx.x;
    __shared__ __align__(16) bf16_t As[2 * 4096];
    __shared__ __align__(16) bf16_t Bs[2 * 4096];

    const int lane = tid & 63;
    const int w    = tid >> 6;
    const int wm   = (w >> 1) * 64;
    const int wn   = (w & 1) * 64;
    const int lr   = lane & 15;
    const int kg   = (lane >> 4) * 8;

    f32x4 acc[4][4];
    #pragma unroll
    for (int a_ = 0; a_ < 4; ++a_)
        #pragma unroll
        for (int b_ = 0; b_ < 4; ++b_)
            acc[a_][b_] = (f32x4){0.f, 0.f, 0.f, 0.f};

    const int eA = tid * 8;
    const int eB = (256 + tid) * 8;
    const int rA = eA >> 5, cA = eA & 31;
    const int rB = eB >> 5, cB = eB & 31;

#define BT_STAGE(buf, kb)                                                       \
    do {                                                                        \
        gload_lds16(A + (size_t)(row0 + rA) * K + (kb) + cA, As + (buf)*4096 + eA); \
        gload_lds16(A + (size_t)(row0 + rB) * K + (kb) + cB, As + (buf)*4096 + eB); \
        gload_lds16(B + (size_t)(col0 + rA) * K + (kb) + cA, Bs + (buf)*4096 + eA); \
        gload_lds16(B + (size_t)(col0 + rB) * K + (kb) + cB, Bs + (buf)*4096 + eB); \
    } while (0)

    BT_STAGE(0, kb0);
    __syncthreads();
    int cur = 0;
    for (int kb = kb0; kb < kb1; kb += 32) {
        if (kb + 32 < kb1) BT_STAGE(cur ^ 1, kb + 32);
        const bf16_t* Ac = As + cur * 4096;
        const bf16_t* Bc = Bs + cur * 4096;

        bf16x8 av[4], bv[4];
        #pragma unroll
        for (int mi = 0; mi < 4; ++mi)
            av[mi] = *(const bf16x8*)(Ac + (wm + mi * 16 + lr) * 32 + kg);
        #pragma unroll
        for (int ni = 0; ni < 4; ++ni)
            bv[ni] = *(const bf16x8*)(Bc + (wn + ni * 16 + lr) * 32 + kg);

        #pragma unroll
        for (int mi = 0; mi < 4; ++mi)
            #pragma unroll
            for (int ni = 0; ni < 4; ++ni)
                acc[mi][ni] = __builtin_amdgcn_mfma_f32_16x16x32_bf16(
                    av[mi], bv[ni], acc[mi][ni], 0, 0, 0);
        __syncthreads();
        cur ^= 1;
    }
#undef BT_STAGE

    float g = 0.f;
    if (EPI == 3) g = gs[0];
    const int cr = (lane >> 4) * 4;
    #pragma unroll
    for (int mi = 0; mi < 4; ++mi) {
        #pragma unroll
        for (int ni = 0; ni < 4; ++ni) {
            const int j = col0 + wn + ni * 16 + lr;
            float s0 = 0.f, s1 = 0.f;
            if (EPI == 2) { s0 = e0[j]; s1 = e1[j]; }
            #pragma unroll
            for (int r = 0; r < 4; ++r) {
                const int i = row0 + wm + mi * 16 + cr + r;
                float v = acc[mi][ni][r];
                if (EPI == 2)      v = v * (1.0f / 1023.0f) / (s0 * s1);
                else if (EPI == 3) v = g * v + e0[(size_t)i * N + j];
                Cz[(size_t)i * N + j] = (OutT)v;
            }
        }
    }
}

// ---------------------------------------------------------------------------
// Row mean/std (ddof=0) of q_on / k_on (each 1024 x 1024 fp32). One wave/row.
__global__ __launch_bounds__(256) void rowstats(
    const float* __restrict__ Q, const float* __restrict__ Km,
    float* __restrict__ qmean, float* __restrict__ qstd,
    float* __restrict__ kmean, float* __restrict__ kstd)
{
    const int wid  = blockIdx.x * 4 + (threadIdx.x >> 6);
    const int lane = threadIdx.x & 63;
    const float* src = (wid < 1024) ? (Q + (size_t)wid * NDIM)
                                    : (Km + (size_t)(wid - 1024) * NDIM);
    float s = 0.f, s2 = 0.f;
    #pragma unroll
    for (int p = 0; p < 4; ++p) {
        float4 v = *(const float4*)(src + p * 256 + lane * 4);
        s  += v.x + v.y + v.z + v.w;
        s2 += v.x * v.x + v.y * v.y + v.z * v.z + v.w * v.w;
    }
    #pragma unroll
    for (int o = 32; o; o >>= 1) { s += __shfl_xor(s, o); s2 += __shfl_xor(s2, o); }
    if (lane == 0) {
        float m   = s / 1024.f;
        float var = fmaxf(s2 / 1024.f - m * m, 0.f);
        if (wid < 1024) { qmean[wid] = m; qstd[wid] = sqrtf(var); }
        else            { kmean[wid - 1024] = m; kstd[wid - 1024] = sqrtf(var); }
    }
}

// ---------------------------------------------------------------------------
// Center by row mean, transpose (o,n)->(n,o), convert bf16. z selects q/k.
__global__ __launch_bounds__(256) void center_tr(
    const float* __restrict__ Q, const float* __restrict__ qmu, bf16_t* __restrict__ qc,
    const float* __restrict__ Km, const float* __restrict__ kmu, bf16_t* __restrict__ kc)
{
    __shared__ float t[32][33];
    const float* M  = blockIdx.z ? Km  : Q;
    const float* mu = blockIdx.z ? kmu : qmu;
    bf16_t* O       = blockIdx.z ? kc  : qc;
    const int o0 = blockIdx.y * 32, n0 = blockIdx.x * 32;
    const int tx = threadIdx.x, ty = threadIdx.y; // block (32,8)
    #pragma unroll
    for (int i = 0; i < 4; ++i) {
        const int o = o0 + ty + i * 8;
        t[ty + i * 8][tx] = M[(size_t)o * NDIM + n0 + tx] - mu[o];
    }
    __syncthreads();
    #pragma unroll
    for (int i = 0; i < 4; ++i)
        O[(size_t)(n0 + ty + i * 8) * C8D + o0 + tx] = (__bf16)t[tx][ty + i * 8];
}

// ---------------------------------------------------------------------------
// Row softmax over the sum of 4 split-K partial P planes -> bf16 A0.
__global__ __launch_bounds__(256) void softmax_rows(const float* __restrict__ P,
                                                    bf16_t* __restrict__ O) {
    const int row = blockIdx.x;
    const int tid = threadIdx.x;
    const size_t PL = (size_t)NDIM * NDIM / 4;   // plane size in float4 units
    const size_t u  = (size_t)row * (NDIM / 4) + tid;
    const float4* B = (const float4*)P;
    float4 p0 = B[u], p1 = B[u + PL], p2 = B[u + 2 * PL], p3 = B[u + 3 * PL];
    float4 v = { p0.x + p1.x + p2.x + p3.x, p0.y + p1.y + p2.y + p3.y,
                 p0.z + p1.z + p2.z + p3.z, p0.w + p1.w + p2.w + p3.w };
    float mx = fmaxf(fmaxf(v.x, v.y), fmaxf(v.z, v.w));
    #pragma unroll
    for (int o = 32; o; o >>= 1) mx = fmaxf(mx, __shfl_xor(mx, o));
    __shared__ float red[8];
    const int w = tid >> 6, lane = tid & 63;
    if (lane == 0) red[w] = mx;
    __syncthreads();
    mx = fmaxf(fmaxf(red[0], red[1]), fmaxf(red[2], red[3]));
    float e0 = __expf(v.x - mx), e1 = __expf(v.y - mx);
    float e2 = __expf(v.z - mx), e3 = __expf(v.w - mx);
    float s = e0 + e1 + e2 + e3;
    #pragma unroll
    for (int o = 32; o; o >>= 1) s += __shfl_xor(s, o);
    if (lane == 0) red[4 + w] = s;
    __syncthreads();
    s = red[4] + red[5] + red[6] + red[7];
    const float inv = 1.0f / s;
    bf16x4 o4 = { (__bf16)(e0 * inv), (__bf16)(e1 * inv),
                  (__bf16)(e2 * inv), (__bf16)(e3 * inv) };
    ((bf16x4*)(O + (size_t)row * NDIM))[tid] = o4;
}

// ---------------------------------------------------------------------------
extern "C" void kernel_launch(void* const* d_in, const int* in_sizes, int n_in,
                              void* d_out, int out_size, void* d_ws, size_t ws_size,
                              hipStream_t stream)
{
    const float* x       = (const float*)d_in[0];
    const float* Wq      = (const float*)d_in[1];
    const float* Wk      = (const float*)d_in[2];
    const float* Wv      = (const float*)d_in[3];
    const float* q_scale = (const float*)d_in[4];
    const float* q_shift = (const float*)d_in[5];
    const float* k_scale = (const float*)d_in[6];
    const float* k_shift = (const float*)d_in[7];
    const float* v_scale = (const float*)d_in[8];
    const float* v_shift = (const float*)d_in[9];
    const float* gamma   = (const float*)d_in[10];
    float* out = (float*)d_out;

    // workspace layout (~65 MB)
    char* w = (char*)d_ws;
    bf16_t* xT   = (bf16_t*)w; w += (size_t)NDIM * CDIM * 2;
    bf16_t* v_b  = (bf16_t*)w; w += (size_t)CDIM * NDIM * 2;
    float*  q_on = (float*) w; w += (size_t)C8D * NDIM * 4;
    float*  k_on = (float*) w; w += (size_t)C8D * NDIM * 4;
    float*  P    = (float*) w; w += (size_t)4 * NDIM * NDIM * 4;  // 4 split-K planes
    bf16_t* qc   = (bf16_t*)w; w += (size_t)NDIM * C8D * 2;
    bf16_t* kc   = (bf16_t*)w; w += (size_t)NDIM * C8D * 2;
    bf16_t* A0   = (bf16_t*)w; w += (size_t)NDIM * NDIM * 2;
    float*  qmean = (float*)w; w += C8D * 4;
    float*  qstd  = (float*)w; w += C8D * 4;
    float*  kmean = (float*)w; w += C8D * 4;
    float*  kstd  = (float*)w; w += C8D * 4;

    // 1. x transpose + bf16 (weights are consumed fp32 directly by mega)
    transpose_cvt_x<<<dim3(NDIM / 32, CDIM / 32), dim3(32, 8), 0, stream>>>(x, xT);

    // 2. mega-GEMM, 256^2 4-phase counted-vmcnt pipeline, fused fp32-A staging
    mega_gemm8<<<dim3(4, MSTACK / 256), 512, 0, stream>>>(
        Wv, Wq, Wk, xT, v_b, q_on, k_on,
        v_scale, v_shift, q_scale, q_shift, k_scale, k_shift);

    // 3. row stats of q_on / k_on (2048 waves)
    rowstats<<<512, 256, 0, stream>>>(q_on, k_on, qmean, qstd, kmean, kstd);

    // 4. center + transpose + bf16
    center_tr<<<dim3(32, 32, 2), dim3(32, 8), 0, stream>>>(
        q_on, qmean, qc, k_on, kmean, kc);

    // 5. P[z] = (qc . kc^T)_z / 1023 / (qstd[j] * kstd[j]), split-K x4 (256 blocks)
    gemm_bt<2, float><<<dim3(NDIM / 128, NDIM / 128, 4), 256, 0, stream>>>(
        qc, kc, P, NDIM, NDIM, C8D, qstd, kstd, nullptr);

    // 6. row softmax over summed partials -> A0 (bf16)
    softmax_rows<<<NDIM, 256, 0, stream>>>(P, A0);

    // 7. out = gamma * (v . A0^T) + x
    gemm_bt<3, float><<<dim3(NDIM / 128, CDIM / 128, 1), 256, 0, stream>>>(
        v_b, A0, out, CDIM, NDIM, NDIM, x, x, gamma);
}

// Round 10
// 350.843 us; speedup vs baseline: 1.5893x; 1.0575x over previous
//
#include <hip/hip_runtime.h>
#include <cstdint>
#include <cstddef>

// Problem dims (fixed)
#define CDIM 8192
#define NDIM 1024   // H*W
#define C8D  1024
#define MSTACK 10240  // 8192 (v) + 1024 (q) + 1024 (k)
#define NT8 128       // K-tiles of 64 in mega GEMM

typedef __bf16 bf16_t;
typedef __bf16 bf16x8 __attribute__((ext_vector_type(8)));
typedef __bf16 bf16x4 __attribute__((ext_vector_type(4)));
typedef float  f32x4  __attribute__((ext_vector_type(4)));

__device__ __forceinline__ void gload_lds16(const void* g, void* l) {
    __builtin_amdgcn_global_load_lds((const __attribute__((address_space(1))) void*)g,
                                     (__attribute__((address_space(3))) void*)l, 16, 0, 0);
}

// ---------------------------------------------------------------------------
// Merged fp32 -> bf16 convert for Wv/Wq/Wk (z selects matrix), grid-stride.
__global__ __launch_bounds__(256) void cvt3_bf16(
    const float* __restrict__ a0, bf16_t* __restrict__ o0, int n80,
    const float* __restrict__ a1, bf16_t* __restrict__ o1, int n81,
    const float* __restrict__ a2, bf16_t* __restrict__ o2, int n82)
{
    const float* in; bf16_t* out; int n8;
    if (blockIdx.z == 0)      { in = a0; out = o0; n8 = n80; }
    else if (blockIdx.z == 1) { in = a1; out = o1; n8 = n81; }
    else                      { in = a2; out = o2; n8 = n82; }
    int idx = blockIdx.x * 256 + threadIdx.x;
    int stride = gridDim.x * 256;
    for (int i = idx; i < n8; i += stride) {
        size_t off = (size_t)i * 8;
        float4 a = *(const float4*)(in + off);
        float4 b = *(const float4*)(in + off + 4);
        bf16x8 o = { (__bf16)a.x, (__bf16)a.y, (__bf16)a.z, (__bf16)a.w,
                     (__bf16)b.x, (__bf16)b.y, (__bf16)b.z, (__bf16)b.w };
        *(bf16x8*)(out + off) = o;
    }
}

// ---------------------------------------------------------------------------
// x (C=8192, N=1024) fp32 -> xT (N, C) bf16, LDS-tiled transpose
__global__ __launch_bounds__(256) void transpose_cvt_x(const float* __restrict__ x,
                                                       bf16_t* __restrict__ xT) {
    __shared__ float t[32][33];
    const int n0 = blockIdx.x * 32, c0 = blockIdx.y * 32;
    const int tx = threadIdx.x, ty = threadIdx.y; // block (32,8)
    #pragma unroll
    for (int i = 0; i < 4; ++i)
        t[ty + i * 8][tx] = x[(size_t)(c0 + ty + i * 8) * NDIM + n0 + tx];
    __syncthreads();
    #pragma unroll
    for (int i = 0; i < 4; ++i)
        xT[(size_t)(n0 + ty + i * 8) * CDIM + c0 + tx] = (__bf16)t[tx][ty + i * 8];
}

// ---------------------------------------------------------------------------
// Mega-GEMM, 256x256 tile, BK=64, 8 waves (2Mx4N), m201-style 4-phase/K-tile
// schedule (verified R6 structure). C[i,j] = sum_k A[i,k]*B[j,k],
// A=[Wv;Wq;Wk] bf16 (M=10240), B=xT. Per K-tile t (slot d=t&1), phases =
// C-quadrants in gray order; 16 MFMA each; one half-tile staged per phase via
// global_load_lds into the slot freed one phase earlier; ONE vmcnt(6) per
// K-tile (3 half-tiles = 6 loads in flight). XOR-swizzle via pre-swizzled
// global source cols (rule #21).
__global__ __launch_bounds__(512, 2) void mega_gemm8(
    const bf16_t* __restrict__ Wv, const bf16_t* __restrict__ Wq,
    const bf16_t* __restrict__ Wk, const bf16_t* __restrict__ Bx,
    bf16_t* __restrict__ v_out, float* __restrict__ q_out, float* __restrict__ k_out,
    const float* __restrict__ v_scale, const float* __restrict__ v_shift,
    const float* __restrict__ q_scale, const float* __restrict__ q_shift,
    const float* __restrict__ k_scale, const float* __restrict__ k_shift)
{
    __shared__ __align__(16) bf16_t Ld[65536];   // A[2][16384] | B[2][16384] @32768

    const int tid  = threadIdx.x;
    const int lane = tid & 63;
    const int wid  = tid >> 6;
    const int wr   = wid >> 2;        // 0..1  (M half within quadrant rows)
    const int wc   = wid & 3;         // 0..3  (N quarter within quadrant cols)

    // XCD-aware bijective swizzle (nwg = 160, %8 == 0; 20 tiles per XCD)
    const int lin  = blockIdx.y * 4 + blockIdx.x;
    const int tile = (lin & 7) * 20 + (lin >> 3);
    const int trow = tile >> 2;
    const int col0 = (tile & 3) * 256;

    const bf16_t* Ag; const float* s0; const float* s1; int arow, path;
    if (trow < 32)      { Ag = Wv; arow = trow * 256;        s0 = v_scale; s1 = v_shift; path = 0; }
    else if (trow < 36) { Ag = Wq; arow = trow * 256 - 8192; s0 = q_scale; s1 = q_shift; path = 1; }
    else                { Ag = Wk; arow = trow * 256 - 9216; s0 = k_scale; s1 = k_shift; path = 2; }

    // staging: half-tile = 128 rows x 64 cols bf16 = 16 KB = 512 thr x 16B x 2
    const int ar0 = tid >> 3;                                  // row 0..63 in 64-chunk
    const int o0  = tid * 8;                                   // LDS elem offset
    const int csw = (((tid & 7) ^ ((tid >> 3) & 7)) << 3);     // pre-swizzled src col

    // read geometry
    const int lr   = lane & 15;
    const int hi8  = (lane >> 4) * 8;
    const int rsw  = (lane & 7) << 3;                          // read-side XOR
    const int ck0  = hi8 ^ rsw;                                // kk=0 col
    const int ck1  = (32 + hi8) ^ rsw;                         // kk=1 col
    const int aRow = wr * 64 + lr;                             // row within A half
    const int bRow = wc * 32 + lr;                             // row within B half

    bf16x8 av[4][2];        // [fi][kk], current mh
    bf16x8 bv[2][2][2];     // [nh][fj][kk], both nh kept live
    f32x4  acc[2][2][4][2]; // [mh][nh][fi][fj]
    #pragma unroll
    for (int mh = 0; mh < 2; ++mh)
        #pragma unroll
        for (int nh = 0; nh < 2; ++nh)
            #pragma unroll
            for (int fi = 0; fi < 4; ++fi)
                #pragma unroll
                for (int fj = 0; fj < 2; ++fj)
                    acc[mh][nh][fi][fj] = (f32x4){0.f, 0.f, 0.f, 0.f};

#define STAGE_AH(BUF, H, KB) do {                                                             \
    gload_lds16(Ag + (size_t)(arow + (H)*128 + ar0     ) * CDIM + (KB) + csw,                 \
                Ld + (BUF)*16384 + (H)*8192 + o0);                                            \
    gload_lds16(Ag + (size_t)(arow + (H)*128 + ar0 + 64) * CDIM + (KB) + csw,                 \
                Ld + (BUF)*16384 + (H)*8192 + o0 + 4096);                                     \
} while (0)

#define STAGE_BH(BUF, H, KB) do {                                                             \
    gload_lds16(Bx + (size_t)(col0 + (H)*128 + ar0     ) * CDIM + (KB) + csw,                 \
                Ld + 32768 + (BUF)*16384 + (H)*8192 + o0);                                    \
    gload_lds16(Bx + (size_t)(col0 + (H)*128 + ar0 + 64) * CDIM + (KB) + csw,                 \
                Ld + 32768 + (BUF)*16384 + (H)*8192 + o0 + 4096);                             \
} while (0)

#define RD_A(BUF, MH) do {                                                                    \
    _Pragma("unroll") for (int fi = 0; fi < 4; ++fi) {                                        \
        av[fi][0] = *(const bf16x8*)(Ld + (BUF)*16384 + ((MH)*128 + aRow + fi*16)*64 + ck0);  \
        av[fi][1] = *(const bf16x8*)(Ld + (BUF)*16384 + ((MH)*128 + aRow + fi*16)*64 + ck1);  \
    }                                                                                         \
} while (0)

#define RD_B(BUF, NH) do {                                                                    \
    _Pragma("unroll") for (int fj = 0; fj < 2; ++fj) {                                        \
        bv[NH][fj][0] = *(const bf16x8*)(Ld + 32768 + (BUF)*16384 +                           \
                                         ((NH)*128 + bRow + fj*16)*64 + ck0);                 \
        bv[NH][fj][1] = *(const bf16x8*)(Ld + 32768 + (BUF)*16384 +                           \
                                         ((NH)*128 + bRow + fj*16)*64 + ck1);                 \
    }                                                                                         \
} while (0)

#define MMA(MH, NH) do {                                                                      \
    __builtin_amdgcn_s_setprio(1);                                                            \
    _Pragma("unroll") for (int kk = 0; kk < 2; ++kk)                                          \
        _Pragma("unroll") for (int fi = 0; fi < 4; ++fi)                                      \
            _Pragma("unroll") for (int fj = 0; fj < 2; ++fj)                                  \
                acc[MH][NH][fi][fj] = __builtin_amdgcn_mfma_f32_16x16x32_bf16(                \
                    av[fi][kk], bv[NH][fj][kk], acc[MH][NH][fi][fj], 0, 0, 0);                \
    __builtin_amdgcn_s_setprio(0);                                                            \
} while (0)

#define SYNC_TOP do {                                                                         \
    __builtin_amdgcn_s_barrier();                                                             \
    asm volatile("s_waitcnt lgkmcnt(0)" ::: "memory");                                        \
    __builtin_amdgcn_sched_barrier(0);                                                        \
} while (0)

#define SYNC_END do {                                                                         \
    __builtin_amdgcn_s_barrier();                                                             \
} while (0)

// One K-tile: 4 quadrant phases. DO_S2: stage tile T+2 (j1..j3). VM: 6 / 0 / -1(none).
#define KTILE(BUF, T, DO_S2, VM) do {                                                         \
    /* j0: quad (0,0) */                                                                      \
    RD_A(BUF, 0); RD_B(BUF, 0);                                                               \
    if ((T) + 1 < NT8) STAGE_BH((BUF)^1, 1, ((T)+1)*64);                                      \
    SYNC_TOP; MMA(0, 0); SYNC_END;                                                            \
    /* j1: quad (0,1) */                                                                      \
    RD_B(BUF, 1);                                                                             \
    if (DO_S2) STAGE_AH(BUF, 0, ((T)+2)*64);                                                  \
    SYNC_TOP; MMA(0, 1); SYNC_END;                                                            \
    /* j2: quad (1,1) */                                                                      \
    RD_A(BUF, 1);                                                                             \
    if (DO_S2) STAGE_BH(BUF, 0, ((T)+2)*64);                                                  \
    SYNC_TOP; MMA(1, 1); SYNC_END;                                                            \
    /* j3: quad (1,0) + per-tile vmcnt */                                                     \
    if (DO_S2) STAGE_AH(BUF, 1, ((T)+2)*64);                                                  \
    SYNC_TOP; MMA(1, 0);                                                                      \
    if ((VM) == 6)      { asm volatile("s_waitcnt vmcnt(6)" ::: "memory");                    \
                          __builtin_amdgcn_sched_barrier(0); }                                \
    else if ((VM) == 0) { asm volatile("s_waitcnt vmcnt(0)" ::: "memory");                    \
                          __builtin_amdgcn_sched_barrier(0); }                                \
    SYNC_END;                                                                                 \
} while (0)

    // prologue: tile0 all 4 halves + tile1's {Ah0,Bh0,Ah1} = 7 half-tiles (14 loads)
    STAGE_AH(0, 0, 0); STAGE_BH(0, 0, 0); STAGE_AH(0, 1, 0); STAGE_BH(0, 1, 0);
    STAGE_AH(1, 0, 64); STAGE_BH(1, 0, 64); STAGE_AH(1, 1, 64);
    asm volatile("s_waitcnt vmcnt(6)" ::: "memory");   // tile0 landed; 3 halves in flight
    __builtin_amdgcn_sched_barrier(0);
    __builtin_amdgcn_s_barrier();

    for (int t = 0; t < NT8 - 2; t += 2) {
        KTILE(0, t,     1, 6);
        KTILE(1, t + 1, 1, 6);
    }
    KTILE(0, NT8 - 2, 0, 0);   // stages only Bh1(127); drain
    KTILE(1, NT8 - 1, 0, -1);  // final tile: no stage, no wait

#undef KTILE
#undef SYNC_END
#undef SYNC_TOP
#undef MMA
#undef RD_B
#undef RD_A
#undef STAGE_BH
#undef STAGE_AH

    // epilogue: C/D layout col = lane&15, row = (lane>>4)*4 + r
    const int cq = (lane >> 4) * 4;
    #pragma unroll
    for (int mh = 0; mh < 2; ++mh) {
        #pragma unroll
        for (int nh = 0; nh < 2; ++nh) {
            #pragma unroll
            for (int fi = 0; fi < 4; ++fi) {
                #pragma unroll
                for (int fj = 0; fj < 2; ++fj) {
                    const int j = col0 + nh * 128 + wc * 32 + fj * 16 + lr;
                    #pragma unroll
                    for (int r = 0; r < 4; ++r) {
                        const int il = arow + mh * 128 + wr * 64 + fi * 16 + cq + r;
                        float vv = acc[mh][nh][fi][fj][r] * s0[il] + s1[il];
                        if (path == 0)      v_out[(size_t)il * NDIM + j] = (__bf16)vv;
                        else if (path == 1) q_out[(size_t)il * NDIM + j] = vv;
                        else                k_out[(size_t)il * NDIM + j] = vv;
                    }
                }
            }
        }
    }
}

// ---------------------------------------------------------------------------
// bt-GEMM: C[i,j] = sum_k A[i,k] * B[j,k]. XCD-swizzled xy grid; optional
// split-K via gridDim.z (each z writes its own partial plane C + z*M*N).
// EPI: 2 = v*(1/1023)/(e0[j]*e1[j])  -> ppmcc partial
//      3 = gs[0]*v + e0[i*N+j]       -> gamma*out + x
template <int EPI, typename OutT>
__global__ __launch_bounds__(256) void gemm_bt(
    const bf16_t* __restrict__ A, const bf16_t* __restrict__ B,
    OutT* __restrict__ C, int M, int N, int K,
    const float* __restrict__ e0, const float* __restrict__ e1,
    const float* __restrict__ gs)
{
    const int gx = gridDim.x;
    const int nwg = gx * gridDim.y;
    const int lin = blockIdx.y * gx + blockIdx.x;
    int tile = lin;
    if ((nwg & 7) == 0) tile = (lin & 7) * (nwg >> 3) + (lin >> 3);
    const int row0 = (tile / gx) * 128;
    const int col0 = (tile % gx) * 128;

    const int Ks  = K / gridDim.z;
    const int kb0 = blockIdx.z * Ks;
    const int kb1 = kb0 + Ks;
    OutT* Cz = C + (size_t)blockIdx.z * M * N;

    const int tid = threadIdx.x;
    __shared__ __align__(16) bf16_t As[2 * 4096];
    __shared__ __align__(16) bf16_t Bs[2 * 4096];

    const int lane = tid & 63;
    const int w    = tid >> 6;
    const int wm   = (w >> 1) * 64;
    const int wn   = (w & 1) * 64;
    const int lr   = lane & 15;
    const int kg   = (lane >> 4) * 8;

    f32x4 acc[4][4];
    #pragma unroll
    for (int a_ = 0; a_ < 4; ++a_)
        #pragma unroll
        for (int b_ = 0; b_ < 4; ++b_)
            acc[a_][b_] = (f32x4){0.f, 0.f, 0.f, 0.f};

    const int eA = tid * 8;
    const int eB = (256 + tid) * 8;
    const int rA = eA >> 5, cA = eA & 31;
    const int rB = eB >> 5, cB = eB & 31;

#define BT_STAGE(buf, kb)                                                       \
    do {                                                                        \
        gload_lds16(A + (size_t)(row0 + rA) * K + (kb) + cA, As + (buf)*4096 + eA); \
        gload_lds16(A + (size_t)(row0 + rB) * K + (kb) + cB, As + (buf)*4096 + eB); \
        gload_lds16(B + (size_t)(col0 + rA) * K + (kb) + cA, Bs + (buf)*4096 + eA); \
        gload_lds16(B + (size_t)(col0 + rB) * K + (kb) + cB, Bs + (buf)*4096 + eB); \
    } while (0)

    BT_STAGE(0, kb0);
    __syncthreads();
    int cur = 0;
    for (int kb = kb0; kb < kb1; kb += 32) {
        if (kb + 32 < kb1) BT_STAGE(cur ^ 1, kb + 32);
        const bf16_t* Ac = As + cur * 4096;
        const bf16_t* Bc = Bs + cur * 4096;

        bf16x8 av[4], bv[4];
        #pragma unroll
        for (int mi = 0; mi < 4; ++mi)
            av[mi] = *(const bf16x8*)(Ac + (wm + mi * 16 + lr) * 32 + kg);
        #pragma unroll
        for (int ni = 0; ni < 4; ++ni)
            bv[ni] = *(const bf16x8*)(Bc + (wn + ni * 16 + lr) * 32 + kg);

        #pragma unroll
        for (int mi = 0; mi < 4; ++mi)
            #pragma unroll
            for (int ni = 0; ni < 4; ++ni)
                acc[mi][ni] = __builtin_amdgcn_mfma_f32_16x16x32_bf16(
                    av[mi], bv[ni], acc[mi][ni], 0, 0, 0);
        __syncthreads();
        cur ^= 1;
    }
#undef BT_STAGE

    float g = 0.f;
    if (EPI == 3) g = gs[0];
    const int cr = (lane >> 4) * 4;
    #pragma unroll
    for (int mi = 0; mi < 4; ++mi) {
        #pragma unroll
        for (int ni = 0; ni < 4; ++ni) {
            const int j = col0 + wn + ni * 16 + lr;
            float s0 = 0.f, s1 = 0.f;
            if (EPI == 2) { s0 = e0[j]; s1 = e1[j]; }
            #pragma unroll
            for (int r = 0; r < 4; ++r) {
                const int i = row0 + wm + mi * 16 + cr + r;
                float v = acc[mi][ni][r];
                if (EPI == 2)      v = v * (1.0f / 1023.0f) / (s0 * s1);
                else if (EPI == 3) v = g * v + e0[(size_t)i * N + j];
                Cz[(size_t)i * N + j] = (OutT)v;
            }
        }
    }
}

// ---------------------------------------------------------------------------
// Row mean/std (ddof=0) of q_on / k_on (each 1024 x 1024 fp32). One wave/row.
__global__ __launch_bounds__(256) void rowstats(
    const float* __restrict__ Q, const float* __restrict__ Km,
    float* __restrict__ qmean, float* __restrict__ qstd,
    float* __restrict__ kmean, float* __restrict__ kstd)
{
    const int wid  = blockIdx.x * 4 + (threadIdx.x >> 6);
    const int lane = threadIdx.x & 63;
    const float* src = (wid < 1024) ? (Q + (size_t)wid * NDIM)
                                    : (Km + (size_t)(wid - 1024) * NDIM);
    float s = 0.f, s2 = 0.f;
    #pragma unroll
    for (int p = 0; p < 4; ++p) {
        float4 v = *(const float4*)(src + p * 256 + lane * 4);
        s  += v.x + v.y + v.z + v.w;
        s2 += v.x * v.x + v.y * v.y + v.z * v.z + v.w * v.w;
    }
    #pragma unroll
    for (int o = 32; o; o >>= 1) { s += __shfl_xor(s, o); s2 += __shfl_xor(s2, o); }
    if (lane == 0) {
        float m   = s / 1024.f;
        float var = fmaxf(s2 / 1024.f - m * m, 0.f);
        if (wid < 1024) { qmean[wid] = m; qstd[wid] = sqrtf(var); }
        else            { kmean[wid - 1024] = m; kstd[wid - 1024] = sqrtf(var); }
    }
}

// ---------------------------------------------------------------------------
// Center by row mean, transpose (o,n)->(n,o), convert bf16. z selects q/k.
__global__ __launch_bounds__(256) void center_tr(
    const float* __restrict__ Q, const float* __restrict__ qmu, bf16_t* __restrict__ qc,
    const float* __restrict__ Km, const float* __restrict__ kmu, bf16_t* __restrict__ kc)
{
    __shared__ float t[32][33];
    const float* M  = blockIdx.z ? Km  : Q;
    const float* mu = blockIdx.z ? kmu : qmu;
    bf16_t* O       = blockIdx.z ? kc  : qc;
    const int o0 = blockIdx.y * 32, n0 = blockIdx.x * 32;
    const int tx = threadIdx.x, ty = threadIdx.y; // block (32,8)
    #pragma unroll
    for (int i = 0; i < 4; ++i) {
        const int o = o0 + ty + i * 8;
        t[ty + i * 8][tx] = M[(size_t)o * NDIM + n0 + tx] - mu[o];
    }
    __syncthreads();
    #pragma unroll
    for (int i = 0; i < 4; ++i)
        O[(size_t)(n0 + ty + i * 8) * C8D + o0 + tx] = (__bf16)t[tx][ty + i * 8];
}

// ---------------------------------------------------------------------------
// Row softmax over the sum of 4 split-K partial P planes -> bf16 A0.
__global__ __launch_bounds__(256) void softmax_rows(const float* __restrict__ P,
                                                    bf16_t* __restrict__ O) {
    const int row = blockIdx.x;
    const int tid = threadIdx.x;
    const size_t PL = (size_t)NDIM * NDIM / 4;   // plane size in float4 units
    const size_t u  = (size_t)row * (NDIM / 4) + tid;
    const float4* B = (const float4*)P;
    float4 p0 = B[u], p1 = B[u + PL], p2 = B[u + 2 * PL], p3 = B[u + 3 * PL];
    float4 v = { p0.x + p1.x + p2.x + p3.x, p0.y + p1.y + p2.y + p3.y,
                 p0.z + p1.z + p2.z + p3.z, p0.w + p1.w + p2.w + p3.w };
    float mx = fmaxf(fmaxf(v.x, v.y), fmaxf(v.z, v.w));
    #pragma unroll
    for (int o = 32; o; o >>= 1) mx = fmaxf(mx, __shfl_xor(mx, o));
    __shared__ float red[8];
    const int w = tid >> 6, lane = tid & 63;
    if (lane == 0) red[w] = mx;
    __syncthreads();
    mx = fmaxf(fmaxf(red[0], red[1]), fmaxf(red[2], red[3]));
    float e0 = __expf(v.x - mx), e1 = __expf(v.y - mx);
    float e2 = __expf(v.z - mx), e3 = __expf(v.w - mx);
    float s = e0 + e1 + e2 + e3;
    #pragma unroll
    for (int o = 32; o; o >>= 1) s += __shfl_xor(s, o);
    if (lane == 0) red[4 + w] = s;
    __syncthreads();
    s = red[4] + red[5] + red[6] + red[7];
    const float inv = 1.0f / s;
    bf16x4 o4 = { (__bf16)(e0 * inv), (__bf16)(e1 * inv),
                  (__bf16)(e2 * inv), (__bf16)(e3 * inv) };
    ((bf16x4*)(O + (size_t)row * NDIM))[tid] = o4;
}

// ---------------------------------------------------------------------------
extern "C" void kernel_launch(void* const* d_in, const int* in_sizes, int n_in,
                              void* d_out, int out_size, void* d_ws, size_t ws_size,
                              hipStream_t stream)
{
    const float* x       = (const float*)d_in[0];
    const float* Wq      = (const float*)d_in[1];
    const float* Wk      = (const float*)d_in[2];
    const float* Wv      = (const float*)d_in[3];
    const float* q_scale = (const float*)d_in[4];
    const float* q_shift = (const float*)d_in[5];
    const float* k_scale = (const float*)d_in[6];
    const float* k_shift = (const float*)d_in[7];
    const float* v_scale = (const float*)d_in[8];
    const float* v_shift = (const float*)d_in[9];
    const float* gamma   = (const float*)d_in[10];
    float* out = (float*)d_out;

    // workspace layout (~230 MB)
    char* w = (char*)d_ws;
    bf16_t* Wv_b = (bf16_t*)w; w += (size_t)CDIM * CDIM * 2;
    bf16_t* Wq_b = (bf16_t*)w; w += (size_t)C8D  * CDIM * 2;
    bf16_t* Wk_b = (bf16_t*)w; w += (size_t)C8D  * CDIM * 2;
    bf16_t* xT   = (bf16_t*)w; w += (size_t)NDIM * CDIM * 2;
    bf16_t* v_b  = (bf16_t*)w; w += (size_t)CDIM * NDIM * 2;
    float*  q_on = (float*) w; w += (size_t)C8D * NDIM * 4;
    float*  k_on = (float*) w; w += (size_t)C8D * NDIM * 4;
    float*  P    = (float*) w; w += (size_t)4 * NDIM * NDIM * 4;  // 4 split-K planes
    bf16_t* qc   = (bf16_t*)w; w += (size_t)NDIM * C8D * 2;
    bf16_t* kc   = (bf16_t*)w; w += (size_t)NDIM * C8D * 2;
    bf16_t* A0   = (bf16_t*)w; w += (size_t)NDIM * NDIM * 2;
    float*  qmean = (float*)w; w += C8D * 4;
    float*  qstd  = (float*)w; w += C8D * 4;
    float*  kmean = (float*)w; w += C8D * 4;
    float*  kstd  = (float*)w; w += C8D * 4;

    // 1. converts (single merged launch) + x transpose
    cvt3_bf16<<<dim3(1024, 1, 3), 256, 0, stream>>>(
        Wv, Wv_b, (int)((size_t)CDIM * CDIM / 8),
        Wq, Wq_b, C8D * CDIM / 8,
        Wk, Wk_b, C8D * CDIM / 8);
    transpose_cvt_x<<<dim3(NDIM / 32, CDIM / 32), dim3(32, 8), 0, stream>>>(x, xT);

    // 2. mega-GEMM, 256^2 4-phase counted-vmcnt pipeline (160 blocks x 512 thr)
    mega_gemm8<<<dim3(4, MSTACK / 256), 512, 0, stream>>>(
        Wv_b, Wq_b, Wk_b, xT, v_b, q_on, k_on,
        v_scale, v_shift, q_scale, q_shift, k_scale, k_shift);

    // 3. row stats of q_on / k_on (2048 waves)
    rowstats<<<512, 256, 0, stream>>>(q_on, k_on, qmean, qstd, kmean, kstd);

    // 4. center + transpose + bf16
    center_tr<<<dim3(32, 32, 2), dim3(32, 8), 0, stream>>>(
        q_on, qmean, qc, k_on, kmean, kc);

    // 5. P[z] = (qc . kc^T)_z / 1023 / (qstd[j] * kstd[j]), split-K x4 (256 blocks)
    gemm_bt<2, float><<<dim3(NDIM / 128, NDIM / 128, 4), 256, 0, stream>>>(
        qc, kc, P, NDIM, NDIM, C8D, qstd, kstd, nullptr);

    // 6. row softmax over summed partials -> A0 (bf16)
    softmax_rows<<<NDIM, 256, 0, stream>>>(P, A0);

    // 7. out = gamma * (v . A0^T) + x
    gemm_bt<3, float><<<dim3(NDIM / 128, CDIM / 128, 1), 256, 0, stream>>>(
        v_b, A0, out, CDIM, NDIM, NDIM, x, x, gamma);
}